// Round 7
// baseline (338.532 us; speedup 1.0000x reference)
//
#include <hip/hip_runtime.h>
#include <math.h>

#define NN 2048
#define DD 512
#define HH 8
#define EE 64

typedef unsigned short u16;
typedef __attribute__((ext_vector_type(8))) short bf16x8;
typedef __attribute__((ext_vector_type(4))) float f32x4;

#define MFMA(a,b,c) __builtin_amdgcn_mfma_f32_16x16x32_bf16((a),(b),(c),0,0,0)

__device__ __forceinline__ float fexp2(float x){
#if __has_builtin(__builtin_amdgcn_exp2f)
  return __builtin_amdgcn_exp2f(x);
#else
  return exp2f(x);
#endif
}

// round-to-nearest-even fp32 -> bf16 (finite inputs only)
__device__ __forceinline__ unsigned rnd1(float x){
  unsigned u = __float_as_uint(x);
  return (u + 0x7fffu + ((u >> 16) & 1u)) >> 16;
}
__device__ __forceinline__ unsigned pk2(float a, float b){
  return rnd1(a) | (rnd1(b) << 16);
}
// truncation pack (P only: small negative bias, in error budget)
__device__ __forceinline__ unsigned tpk2(float a, float b){
  return (__float_as_uint(a) >> 16) | (__float_as_uint(b) & 0xffff0000u);
}
union I4V { int4 i; bf16x8 v; };
__device__ __forceinline__ bf16x8 ld_frag(const u16* p){
  I4V u; u.i = *(const int4*)p; return u.v;
}
__device__ __forceinline__ bf16x8 mk_frag(int a, int b, int c, int d){
  I4V u; u.i = make_int4(a,b,c,d); return u.v;
}

// ===========================================================================
// Packed fragment layouts (lane = q*16+jl; chunk = 8 k-contiguous bf16 = 16B):
//  wpk [p][h][kc16][es4][lane][8] : W_p[h][e=es*16+jl][d=kc*32+q*8+jj]  (Wq scaled)
//  wopk[ot8][kc16][os4][lane][8]  : Wo[h=k>>6][o=ot*64+os*16+jl][e=k&63], k=kc*32+q*8+jj
//  xpk [p][b][ng128][kc16][lane][8] : X_p[b][n=ng*16+jl][d=kc*32+q*8+jj]
//  Qpk/Kpk[bh][ng128][kh2][lane][8] : Q[bh][n=ng*16+jl][e=kh*32+q*8+jj]
//  Vpk [bh][jt32][jc2][es4][lane][8]: V[bh][j=jt*64+jc*32+q*8+jj][e=es*16+jl]
//  Rpk [rg512][kc16][lane][8]       : rep[r=rg*16+jl][k=h*64+e=kc*32+q*8+jj]
// ===========================================================================

// ---------------------------------------------------------------------------
// Weight pre-convert+pack.  grid (128, 4), 256 thr.
// ---------------------------------------------------------------------------
__global__ __launch_bounds__(256) void precvt_kernel(
    const float* __restrict__ Wq, const float* __restrict__ Wk,
    const float* __restrict__ Wv, const float* __restrict__ Wo,
    u16* __restrict__ wpk, u16* __restrict__ wopk)
{
  const int tid = blockIdx.x * 256 + threadIdx.x;   // 0..32767
  const int seg = blockIdx.y;
  const int lane = tid & 63, jl = lane & 15, q = lane >> 4;
  const int es = (tid >> 6) & 3, kc = (tid >> 8) & 15, hh = tid >> 12;

  if (seg < 3) {
    const float* Wsrc = (seg == 0) ? Wq : (seg == 1) ? Wk : Wv;
    const float s = (seg == 0) ? 0.18033688011112042f : 1.0f;  // log2e/sqrt(E)
    const float* src = Wsrc + ((size_t)hh * 64 + es * 16 + jl) * DD + kc * 32 + q * 8;
    float4 fa = *(const float4*)src;
    float4 fb = *(const float4*)(src + 4);
    int4 pk = make_int4(pk2(fa.x*s, fa.y*s), pk2(fa.z*s, fa.w*s),
                        pk2(fb.x*s, fb.y*s), pk2(fb.z*s, fb.w*s));
    *(int4*)&wpk[(size_t)(((seg*8 + hh)*16 + kc)*4 + es)*512 + lane*8] = pk;
  } else {
    const int k = kc * 32 + q * 8;           // h = k>>6, e = k&63 (8 contiguous)
    const float* src = Wo + ((size_t)(k >> 6) * DD + hh * 64 + es * 16 + jl) * EE + (k & 63);
    float4 fa = *(const float4*)src;
    float4 fb = *(const float4*)(src + 4);
    int4 pk = make_int4(pk2(fa.x, fa.y), pk2(fa.z, fa.w),
                        pk2(fb.x, fb.y), pk2(fb.z, fb.w));
    *(int4*)&wopk[(size_t)(((hh*16 + kc)*4 + es)*512) + lane*8] = pk;
  }
}

// ---------------------------------------------------------------------------
// x pack: fp32 [b][n][d] -> bf16 B-fragments via LDS transpose.
// grid (32 nt, 8 dt, 12 p*4+b).  Block: 64n x 64d tile.
// ---------------------------------------------------------------------------
__global__ __launch_bounds__(256) void xpack_kernel(
    const float* __restrict__ x1, const float* __restrict__ x2,
    const float* __restrict__ vin, u16* __restrict__ xpk)
{
  __shared__ float lds[64][68];
  const int nt = blockIdx.x, dt = blockIdx.y, pb = blockIdx.z;
  const int p = pb >> 2, b = pb & 3;
  const float* X = (p == 0) ? x2 : (p == 1) ? x1 : vin;
  const int t = threadIdx.x;

  {
    const int r = t >> 2, c0 = (t & 3) * 16;
    const float* src = X + ((size_t)b * NN + nt * 64 + r) * DD + dt * 64 + c0;
    float4 f0 = ((const float4*)src)[0];
    float4 f1 = ((const float4*)src)[1];
    float4 f2 = ((const float4*)src)[2];
    float4 f3 = ((const float4*)src)[3];
    *(float4*)&lds[r][c0]      = f0;
    *(float4*)&lds[r][c0 + 4]  = f1;
    *(float4*)&lds[r][c0 + 8]  = f2;
    *(float4*)&lds[r][c0 + 12] = f3;
  }
  __syncthreads();

  const int lane = t & 63, w = t >> 6, jl = lane & 15, q = lane >> 4;
  #pragma unroll
  for (int kcl = 0; kcl < 2; ++kcl) {
    float4 fa = *(const float4*)&lds[w * 16 + jl][kcl * 32 + q * 8];
    float4 fb = *(const float4*)&lds[w * 16 + jl][kcl * 32 + q * 8 + 4];
    int4 pk = make_int4(pk2(fa.x, fa.y), pk2(fa.z, fa.w),
                        pk2(fb.x, fb.y), pk2(fb.z, fb.w));
    const int ng = nt * 4 + w, kc = dt * 2 + kcl;
    *(int4*)&xpk[((((size_t)pb * 128 + ng) * 16 + kc) * 64 + lane) * 8] = pk;
  }
}

// ---------------------------------------------------------------------------
// Q/K/V projection: fully packed operands, no LDS.  grid (128: b*32+nt, 24: p*8+h).
// A = W-frag (L1-broadcast across waves/blocks), B = x-frag.  D rows=e, cols=n.
// (round-5 form; the round-6 h-batch variant regressed)
// ---------------------------------------------------------------------------
__global__ __launch_bounds__(256) void qkvproj_kernel(
    const u16* __restrict__ xpk, const u16* __restrict__ wpk,
    u16* __restrict__ Qpk, u16* __restrict__ Kpk, u16* __restrict__ Vpk)
{
  const int t = threadIdx.x, w = t >> 6, lane = t & 63;
  const int jl = lane & 15, q = lane >> 4;
  const int bn = blockIdx.x, ph = blockIdx.y;
  const int b = bn >> 5, nt = bn & 31, p = ph >> 3, h = ph & 7;

  const u16* xb = xpk + (((size_t)(p * 4 + b) * 128 + nt * 4 + w) * 16) * 512;
  const u16* wb = wpk + (size_t)ph * 32768;

  f32x4 acc[4];
  #pragma unroll
  for (int i = 0; i < 4; ++i) acc[i] = (f32x4){0.f,0.f,0.f,0.f};

  #pragma unroll 4
  for (int kc = 0; kc < 16; ++kc) {
    bf16x8 xf = ld_frag(xb + kc * 512 + lane * 8);
    #pragma unroll
    for (int es = 0; es < 4; ++es) {
      bf16x8 wf = ld_frag(wb + (size_t)(kc * 4 + es) * 512 + lane * 8);
      acc[es] = MFMA(wf, xf, acc[es]);
    }
  }

  const int bh = b * 8 + h;
  if (p < 2) {
    // D: row e = es*16+q*4+r, col n = (nt*4+w)*16 + jl  ->  packed Q/K
    u16* O = (p ? Kpk : Qpk) + (size_t)bh * 131072;
    const int ng = nt * 4 + w;
    #pragma unroll
    for (int es = 0; es < 4; ++es) {
      const int kh = es >> 1, qp = (es & 1) * 2 + (q >> 1), off = (q & 1) * 4;
      *(uint2*)&O[(size_t)((ng * 2 + kh) * 64 + qp * 16 + jl) * 8 + off] =
          make_uint2(pk2(acc[es][0], acc[es][1]), pk2(acc[es][2], acc[es][3]));
    }
  } else {
    // D: row e = es*16+q*4+r, col j = nt*64 + w*16 + jl  ->  packed V
    u16* O = Vpk + (size_t)bh * 131072 + nt * 4096;
    const int jc = w >> 1, qp = (w & 1) * 2 + (jl >> 3), jj = jl & 7;
    #pragma unroll
    for (int es = 0; es < 4; ++es)
      #pragma unroll
      for (int r = 0; r < 4; ++r)
        O[(size_t)((jc * 4 + es) * 64 + qp * 16 + q * 4 + r) * 8 + jj] =
            (u16)rnd1(acc[es][r]);
  }
}

// ---------------------------------------------------------------------------
// Attention: per (bh, 64-row i-tile); 4 waves split j (512 each).
// Software-pipelined: K[jt+1] fragments double-buffered (loads in flight
// across the whole exp+PV phase); V[jt] loads issued before the S phase so
// exp/pack covers their latency.  NO forced occupancy bound — round 6 proved
// spill-free > third wave.  P truncation-packed through per-wave LDS.
// ---------------------------------------------------------------------------
__global__ __launch_bounds__(256, 2) void attn_kernel(
    const u16* __restrict__ Qpk, const u16* __restrict__ Kpk,
    const u16* __restrict__ Vpk, u16* __restrict__ Rpk)
{
  __shared__ union {
    short P[4][64][76];       // per-wave 64x64 P tile, stride 76 bf16 (152 B)
    float slab[2][64 * 65];   // combine scratch (overlays dead P regions)
  } sh;
  __shared__ float lbuf[4][64];

  const int tid = threadIdx.x, w = tid >> 6, lane = tid & 63;
  const int jl = lane & 15, q = lane >> 4;
  const int bx = blockIdx.x;
  const int itile = bx >> 5;        // bh fast: XCD sees fixed bh mod 8 -> L2 locality
  const int bh = bx & 31;
  const int b = bh >> 3, h = bh & 7;

  // Q fragments (persistent; 32 VGPRs)
  const u16* Qp = Qpk + ((size_t)bh * 128 + itile * 4) * 1024;
  bf16x8 qf[4][2];
  #pragma unroll
  for (int is = 0; is < 4; ++is) {
    qf[is][0] = ld_frag(Qp + is * 1024 + lane * 8);
    qf[is][1] = ld_frag(Qp + is * 1024 + 512 + lane * 8);
  }

  const u16* Kp = Kpk + (size_t)bh * 131072 + (size_t)w * 32768;
  const u16* Vp = Vpk + (size_t)bh * 131072 + (size_t)w * 32768;

  char* pw = (char*)&sh.P[0][0][0] + w * 9728 + jl * 152 + q * 8;
  const char* pr = (const char*)&sh.P[0][0][0] + w * 9728 + jl * 152 + q * 16;

  f32x4 acc[4][4];
  #pragma unroll
  for (int m = 0; m < 4; ++m)
    #pragma unroll
    for (int e = 0; e < 4; ++e) acc[m][e] = (f32x4){0.f,0.f,0.f,0.f};
  float lac[4] = {0.f, 0.f, 0.f, 0.f};

  // ---- K double-buffer: preload jt=0 ----
  bf16x8 kf[2][4][2];
  #pragma unroll
  for (int jm = 0; jm < 4; ++jm) {
    kf[0][jm][0] = ld_frag(Kp + jm * 1024 + lane * 8);
    kf[0][jm][1] = ld_frag(Kp + jm * 1024 + 512 + lane * 8);
  }

  #pragma unroll
  for (int jt = 0; jt < 8; ++jt) {
    const int cur = jt & 1, nxt = cur ^ 1;
    // ---- prefetch K[jt+1]: consumed next iteration (~1300 cyc away) ----
    if (jt < 7) {
      const u16* Kn = Kp + (jt + 1) * 4096;
      #pragma unroll
      for (int jm = 0; jm < 4; ++jm) {
        kf[nxt][jm][0] = ld_frag(Kn + jm * 1024 + lane * 8);
        kf[nxt][jm][1] = ld_frag(Kn + jm * 1024 + 512 + lane * 8);
      }
    }
    // ---- V[jt] loads: issued before S phase, consumed after exp/pack ----
    const u16* Vb = Vp + jt * 4096;
    bf16x8 vf[4][2];
    #pragma unroll
    for (int es = 0; es < 4; ++es) {
      vf[es][0] = ld_frag(Vb + es * 512 + lane * 8);
      vf[es][1] = ld_frag(Vb + 2048 + es * 512 + lane * 8);
    }
    // ---- S^T = K*Q^T, exp2, P -> LDS (A-operand layout, trunc pack) ----
    #pragma unroll
    for (int jm = 0; jm < 4; ++jm) {
      #pragma unroll
      for (int is = 0; is < 4; ++is) {
        f32x4 c = (f32x4){0.f,0.f,0.f,0.f};
        c = MFMA(kf[cur][jm][0], qf[is][0], c);
        c = MFMA(kf[cur][jm][1], qf[is][1], c);
        float e0 = fexp2(c[0]), e1 = fexp2(c[1]);
        float e2 = fexp2(c[2]), e3 = fexp2(c[3]);
        lac[is] += (e0 + e1) + (e2 + e3);
        int2 pv; pv.x = tpk2(e0, e1); pv.y = tpk2(e2, e3);
        *(int2*)(pw + is * 2432 + jm * 32) = pv;
      }
    }
    // ---- rep += P * V ----
    #pragma unroll
    for (int m = 0; m < 4; ++m) {
      int2 a0 = *(const int2*)(pr + m * 2432);
      int2 a1 = *(const int2*)(pr + m * 2432 + 8);
      int2 a2 = *(const int2*)(pr + m * 2432 + 64);
      int2 a3 = *(const int2*)(pr + m * 2432 + 72);
      bf16x8 p0 = mk_frag(a0.x, a0.y, a1.x, a1.y);
      bf16x8 p1 = mk_frag(a2.x, a2.y, a3.x, a3.y);
      #pragma unroll
      for (int es = 0; es < 4; ++es) {
        acc[m][es] = MFMA(p0, vf[es][0], acc[m][es]);
        acc[m][es] = MFMA(p1, vf[es][1], acc[m][es]);
      }
    }
  }

  #pragma unroll
  for (int is = 0; is < 4; ++is) {
    float lv = lac[is];
    lv += __shfl_xor(lv, 16, 64);
    lv += __shfl_xor(lv, 32, 64);
    if (lane < 16) lbuf[w][is * 16 + lane] = lv;
  }
  __syncthreads();

  if (w >= 2) {
    float* s = sh.slab[w - 2];
    #pragma unroll
    for (int m = 0; m < 4; ++m)
      #pragma unroll
      for (int es = 0; es < 4; ++es)
        #pragma unroll
        for (int r = 0; r < 4; ++r)
          s[(m * 16 + q * 4 + r) * 65 + es * 16 + jl] = acc[m][es][r];
  }
  __syncthreads();
  if (w < 2) {
    const float* s = sh.slab[w];
    #pragma unroll
    for (int m = 0; m < 4; ++m)
      #pragma unroll
      for (int es = 0; es < 4; ++es)
        #pragma unroll
        for (int r = 0; r < 4; ++r)
          acc[m][es][r] += s[(m * 16 + q * 4 + r) * 65 + es * 16 + jl];
  }
  __syncthreads();
  if (w == 1) {
    float* s = sh.slab[0];
    #pragma unroll
    for (int m = 0; m < 4; ++m)
      #pragma unroll
      for (int es = 0; es < 4; ++es)
        #pragma unroll
        for (int r = 0; r < 4; ++r)
          s[(m * 16 + q * 4 + r) * 65 + es * 16 + jl] = acc[m][es][r];
  }
  __syncthreads();
  if (w == 0) {
    const float* s = sh.slab[0];
    #pragma unroll
    for (int m = 0; m < 4; ++m) {
      float il[4];
      #pragma unroll
      for (int r = 0; r < 4; ++r) {
        const int i = m * 16 + q * 4 + r;
        il[r] = 1.0f / (lbuf[0][i] + lbuf[1][i] + lbuf[2][i] + lbuf[3][i]);
      }
      const int rg = b * 128 + itile * 4 + m;
      #pragma unroll
      for (int es = 0; es < 4; ++es) {
        const int kc = h * 2 + (es >> 1);
        const int qp = (es & 1) * 2 + (jl >> 3), jj = jl & 7;
        #pragma unroll
        for (int r = 0; r < 4; ++r) {
          float val = (acc[m][es][r] + s[(m * 16 + q * 4 + r) * 65 + es * 16 + jl]) * il[r];
          Rpk[((size_t)rg * 16 + kc) * 512 + (size_t)(qp * 16 + q * 4 + r) * 8 + jj] =
              (u16)rnd1(val);
        }
      }
    }
  }
}

// ---------------------------------------------------------------------------
// Output projection: fully packed, no LDS.  grid (128 rt, 8 ot) (round-5 form).
// ---------------------------------------------------------------------------
__global__ __launch_bounds__(256) void outproj_kernel(
    const u16* __restrict__ Rpk, const u16* __restrict__ wopk,
    float* __restrict__ out)
{
  const int t = threadIdx.x, w = t >> 6, lane = t & 63;
  const int jl = lane & 15, q = lane >> 4;
  const int rt = blockIdx.x, ot = blockIdx.y;
  const int rg = rt * 4 + w;

  f32x4 acc[4];
  #pragma unroll
  for (int i = 0; i < 4; ++i) acc[i] = (f32x4){0.f,0.f,0.f,0.f};

  #pragma unroll 4
  for (int kc = 0; kc < 16; ++kc) {
    bf16x8 bf = ld_frag(Rpk + ((size_t)rg * 16 + kc) * 512 + lane * 8);
    #pragma unroll
    for (int os = 0; os < 4; ++os) {
      bf16x8 wf = ld_frag(wopk + (size_t)((ot * 16 + kc) * 4 + os) * 512 + lane * 8);
      acc[os] = MFMA(wf, bf, acc[os]);
    }
  }

  #pragma unroll
  for (int os = 0; os < 4; ++os) {   // D row = o = os*16+q*4+r, col = r-row = jl
    float4 o4 = make_float4(acc[os][0], acc[os][1], acc[os][2], acc[os][3]);
    *(float4*)&out[(size_t)(rt * 64 + w * 16 + jl) * DD + ot * 64 + os * 16 + q * 4] = o4;
  }
}

// ---------------------------------------------------------------------------
extern "C" void kernel_launch(void* const* d_in, const int* in_sizes, int n_in,
                              void* d_out, int out_size, void* d_ws, size_t ws_size,
                              hipStream_t stream)
{
  const float* x1 = (const float*)d_in[0];
  const float* x2 = (const float*)d_in[1];
  const float* vv = (const float*)d_in[2];
  const float* Wq = (const float*)d_in[3];
  const float* Wk = (const float*)d_in[4];
  const float* Wv = (const float*)d_in[5];
  const float* Wo = (const float*)d_in[6];
  float* out = (float*)d_out;

  char* W = (char*)d_ws;                        // ~58 MB total
  u16* wpk  = (u16*)(W);                        // 1.5 MB
  u16* wopk = (u16*)(W + 1572864);              // 0.5 MB
  u16* xpk  = (u16*)(W + 2097152);              // 24 MB
  u16* Qpk  = (u16*)(W + 27262976);             // 8 MB
  u16* Kpk  = (u16*)(W + 35651584);             // 8 MB
  u16* Vpk  = (u16*)(W + 44040192);             // 8 MB
  u16* Rpk  = (u16*)(W + 52428800);             // 8 MB

  precvt_kernel <<<dim3(128, 4), 256, 0, stream>>>(Wq, Wk, Wv, Wo, wpk, wopk);
  xpack_kernel  <<<dim3(32, 8, 12), 256, 0, stream>>>(x1, x2, vv, xpk);
  qkvproj_kernel<<<dim3(128, 24), 256, 0, stream>>>(xpk, wpk, Qpk, Kpk, Vpk);
  attn_kernel   <<<dim3(1024), 256, 0, stream>>>(Qpk, Kpk, Vpk, Rpk);
  outproj_kernel<<<dim3(128, 8), 256, 0, stream>>>(Rpk, wopk, out);
}

// Round 8
// 189.262 us; speedup vs baseline: 1.7887x; 1.7887x over previous
//
#include <hip/hip_runtime.h>
#include <math.h>

#define NN 2048
#define DD 512
#define HH 8
#define EE 64

typedef unsigned short u16;
typedef __attribute__((ext_vector_type(8))) short bf16x8;
typedef __attribute__((ext_vector_type(4))) float f32x4;

#define MFMA(a,b,c) __builtin_amdgcn_mfma_f32_16x16x32_bf16((a),(b),(c),0,0,0)

__device__ __forceinline__ float fexp2(float x){
#if __has_builtin(__builtin_amdgcn_exp2f)
  return __builtin_amdgcn_exp2f(x);
#else
  return exp2f(x);
#endif
}

// round-to-nearest-even fp32 -> bf16 (finite inputs only)
__device__ __forceinline__ unsigned rnd1(float x){
  unsigned u = __float_as_uint(x);
  return (u + 0x7fffu + ((u >> 16) & 1u)) >> 16;
}
__device__ __forceinline__ unsigned pk2(float a, float b){
  return rnd1(a) | (rnd1(b) << 16);
}
// truncation pack (P only: small negative bias, in error budget)
__device__ __forceinline__ unsigned tpk2(float a, float b){
  return (__float_as_uint(a) >> 16) | (__float_as_uint(b) & 0xffff0000u);
}
union I4V { int4 i; bf16x8 v; };
__device__ __forceinline__ bf16x8 ld_frag(const u16* p){
  I4V u; u.i = *(const int4*)p; return u.v;
}
__device__ __forceinline__ bf16x8 mk_frag(int a, int b, int c, int d){
  I4V u; u.i = make_int4(a,b,c,d); return u.v;
}

// ===========================================================================
// Packed fragment layouts (lane = q*16+jl; chunk = 8 k-contiguous bf16 = 16B):
//  wpk [p][h][kc16][es4][lane][8] : W_p[h][e=es*16+jl][d=kc*32+q*8+jj]  (Wq scaled)
//  wopk[ot8][kc16][os4][lane][8]  : Wo[h=k>>6][o=ot*64+os*16+jl][e=k&63], k=kc*32+q*8+jj
//  xpk [p][b][ng128][kc16][lane][8] : X_p[b][n=ng*16+jl][d=kc*32+q*8+jj]
//  Qpk/Kpk[bh][ng128][kh2][lane][8] : Q[bh][n=ng*16+jl][e=kh*32+q*8+jj]
//  Vpk [bh][jt32][jc2][es4][lane][8]: V[bh][j=jt*64+jc*32+q*8+jj][e=es*16+jl]
//  Rpk [rg512][kc16][lane][8]       : rep[r=rg*16+jl][k=h*64+e=kc*32+q*8+jj]
// ===========================================================================

// ---------------------------------------------------------------------------
// Pack kernel: z<12 = x pack (fp32 -> bf16 B-frags via LDS transpose),
// z in {12,13} = weight pre-convert+pack (merged former precvt launch).
// grid (32, 8, 14), 256 thr.
// ---------------------------------------------------------------------------
__global__ __launch_bounds__(256) void pack_kernel(
    const float* __restrict__ x1, const float* __restrict__ x2,
    const float* __restrict__ vin,
    const float* __restrict__ Wq, const float* __restrict__ Wk,
    const float* __restrict__ Wv, const float* __restrict__ Wo,
    u16* __restrict__ xpk, u16* __restrict__ wpk, u16* __restrict__ wopk)
{
  __shared__ float lds[64][68];
  const int z = blockIdx.z;
  const int t = threadIdx.x;

  if (z < 12) {
    // ---- x pack: block handles a 64n x 64d tile of input pb ----
    const int nt = blockIdx.x, dt = blockIdx.y, pb = z;
    const int p = pb >> 2, b = pb & 3;
    const float* X = (p == 0) ? x2 : (p == 1) ? x1 : vin;

    {
      const int r = t >> 2, c0 = (t & 3) * 16;
      const float* src = X + ((size_t)b * NN + nt * 64 + r) * DD + dt * 64 + c0;
      float4 f0 = ((const float4*)src)[0];
      float4 f1 = ((const float4*)src)[1];
      float4 f2 = ((const float4*)src)[2];
      float4 f3 = ((const float4*)src)[3];
      *(float4*)&lds[r][c0]      = f0;
      *(float4*)&lds[r][c0 + 4]  = f1;
      *(float4*)&lds[r][c0 + 8]  = f2;
      *(float4*)&lds[r][c0 + 12] = f3;
    }
    __syncthreads();

    const int lane = t & 63, w = t >> 6, jl = lane & 15, q = lane >> 4;
    #pragma unroll
    for (int kcl = 0; kcl < 2; ++kcl) {
      float4 fa = *(const float4*)&lds[w * 16 + jl][kcl * 32 + q * 8];
      float4 fb = *(const float4*)&lds[w * 16 + jl][kcl * 32 + q * 8 + 4];
      int4 pk = make_int4(pk2(fa.x, fa.y), pk2(fa.z, fa.w),
                          pk2(fb.x, fb.y), pk2(fb.z, fb.w));
      const int ng = nt * 4 + w, kc = dt * 2 + kcl;
      *(int4*)&xpk[((((size_t)pb * 128 + ng) * 16 + kc) * 64 + lane) * 8] = pk;
    }
  } else {
    // ---- weight pack ----
    const int zi = (z - 12) * 256 + blockIdx.y * 32 + blockIdx.x;  // 0..511
    const int gid = zi * 256 + t;                                  // 0..131071
    const int seg = gid >> 15, tid = gid & 32767;
    const int lane = tid & 63, jl = lane & 15, q = lane >> 4;
    const int es = (tid >> 6) & 3, kc = (tid >> 8) & 15, hh = tid >> 12;

    if (seg < 3) {
      const float* Wsrc = (seg == 0) ? Wq : (seg == 1) ? Wk : Wv;
      const float s = (seg == 0) ? 0.18033688011112042f : 1.0f;  // log2e/sqrt(E)
      const float* src = Wsrc + ((size_t)hh * 64 + es * 16 + jl) * DD + kc * 32 + q * 8;
      float4 fa = *(const float4*)src;
      float4 fb = *(const float4*)(src + 4);
      int4 pk = make_int4(pk2(fa.x*s, fa.y*s), pk2(fa.z*s, fa.w*s),
                          pk2(fb.x*s, fb.y*s), pk2(fb.z*s, fb.w*s));
      *(int4*)&wpk[(size_t)(((seg*8 + hh)*16 + kc)*4 + es)*512 + lane*8] = pk;
    } else {
      const int k = kc * 32 + q * 8;           // h = k>>6, e = k&63 (8 contiguous)
      const float* src = Wo + ((size_t)(k >> 6) * DD + hh * 64 + es * 16 + jl) * EE + (k & 63);
      float4 fa = *(const float4*)src;
      float4 fb = *(const float4*)(src + 4);
      int4 pk = make_int4(pk2(fa.x, fa.y), pk2(fa.z, fa.w),
                          pk2(fb.x, fb.y), pk2(fb.z, fb.w));
      *(int4*)&wopk[(size_t)(((hh*16 + kc)*4 + es)*512) + lane*8] = pk;
    }
  }
}

// ---------------------------------------------------------------------------
// Q/K/V projection: fully packed operands, no LDS.  grid (128: b*32+nt, 24: p*8+h).
// A = W-frag (L2-shared across blocks with same h), B = x-frag.  D rows=e, cols=n.
// (round-5 form, known good)
// ---------------------------------------------------------------------------
__global__ __launch_bounds__(256) void qkvproj_kernel(
    const u16* __restrict__ xpk, const u16* __restrict__ wpk,
    u16* __restrict__ Qpk, u16* __restrict__ Kpk, u16* __restrict__ Vpk)
{
  const int t = threadIdx.x, w = t >> 6, lane = t & 63;
  const int jl = lane & 15, q = lane >> 4;
  const int bn = blockIdx.x, ph = blockIdx.y;
  const int b = bn >> 5, nt = bn & 31, p = ph >> 3, h = ph & 7;

  const u16* xb = xpk + (((size_t)(p * 4 + b) * 128 + nt * 4 + w) * 16) * 512;
  const u16* wb = wpk + (size_t)ph * 32768;

  f32x4 acc[4];
  #pragma unroll
  for (int i = 0; i < 4; ++i) acc[i] = (f32x4){0.f,0.f,0.f,0.f};

  #pragma unroll 4
  for (int kc = 0; kc < 16; ++kc) {
    bf16x8 xf = ld_frag(xb + kc * 512 + lane * 8);
    #pragma unroll
    for (int es = 0; es < 4; ++es) {
      bf16x8 wf = ld_frag(wb + (size_t)(kc * 4 + es) * 512 + lane * 8);
      acc[es] = MFMA(wf, xf, acc[es]);
    }
  }

  const int bh = b * 8 + h;
  if (p < 2) {
    // D: row e = es*16+q*4+r, col n = (nt*4+w)*16 + jl  ->  packed Q/K
    u16* O = (p ? Kpk : Qpk) + (size_t)bh * 131072;
    const int ng = nt * 4 + w;
    #pragma unroll
    for (int es = 0; es < 4; ++es) {
      const int kh = es >> 1, qp = (es & 1) * 2 + (q >> 1), off = (q & 1) * 4;
      *(uint2*)&O[(size_t)((ng * 2 + kh) * 64 + qp * 16 + jl) * 8 + off] =
          make_uint2(pk2(acc[es][0], acc[es][1]), pk2(acc[es][2], acc[es][3]));
    }
  } else {
    // D: row e = es*16+q*4+r, col j = nt*64 + w*16 + jl  ->  packed V
    u16* O = Vpk + (size_t)bh * 131072 + nt * 4096;
    const int jc = w >> 1, qp = (w & 1) * 2 + (jl >> 3), jj = jl & 7;
    #pragma unroll
    for (int es = 0; es < 4; ++es)
      #pragma unroll
      for (int r = 0; r < 4; ++r)
        O[(size_t)((jc * 4 + es) * 64 + qp * 16 + q * 4 + r) * 8 + jj] =
            (u16)rnd1(acc[es][r]);
  }
}

// ---------------------------------------------------------------------------
// Attention: per (bh, 64-row i-tile); 4 waves split j (512 each).
// Issue-slot pipelining with ZERO extra buffers (rounds 6/7 proved the
// register ceiling): V[jt] loads issue before the S phase (latency hidden by
// MFMA+exp); K[jt+1] reloads IN PLACE into the same kf regs right after the
// S phase's last use (WAR reuse, latency hidden by the PV phase).
// jt loop stays rolled.  P truncation-packed through per-wave LDS.
// ---------------------------------------------------------------------------
__global__ __launch_bounds__(256, 2) void attn_kernel(
    const u16* __restrict__ Qpk, const u16* __restrict__ Kpk,
    const u16* __restrict__ Vpk, u16* __restrict__ Rpk)
{
  __shared__ union {
    short P[4][64][76];       // per-wave 64x64 P tile, stride 76 bf16 (152 B)
    float slab[2][64 * 65];   // combine scratch (overlays dead P regions)
  } sh;
  __shared__ float lbuf[4][64];

  const int tid = threadIdx.x, w = tid >> 6, lane = tid & 63;
  const int jl = lane & 15, q = lane >> 4;
  const int bx = blockIdx.x;
  const int itile = bx >> 5;        // bh fast: XCD sees fixed bh mod 8 -> L2 locality
  const int bh = bx & 31;
  const int b = bh >> 3, h = bh & 7;

  // Q fragments (persistent; 32 VGPRs)
  const u16* Qp = Qpk + ((size_t)bh * 128 + itile * 4) * 1024;
  bf16x8 qf[4][2];
  #pragma unroll
  for (int is = 0; is < 4; ++is) {
    qf[is][0] = ld_frag(Qp + is * 1024 + lane * 8);
    qf[is][1] = ld_frag(Qp + is * 1024 + 512 + lane * 8);
  }

  const u16* Kp = Kpk + (size_t)bh * 131072 + (size_t)w * 32768;
  const u16* Vp = Vpk + (size_t)bh * 131072 + (size_t)w * 32768;

  char* pw = (char*)&sh.P[0][0][0] + w * 9728 + jl * 152 + q * 8;
  const char* pr = (const char*)&sh.P[0][0][0] + w * 9728 + jl * 152 + q * 16;

  f32x4 acc[4][4];
  #pragma unroll
  for (int m = 0; m < 4; ++m)
    #pragma unroll
    for (int e = 0; e < 4; ++e) acc[m][e] = (f32x4){0.f,0.f,0.f,0.f};
  float lac[4] = {0.f, 0.f, 0.f, 0.f};

  // ---- single K buffer: preload jt=0 ----
  bf16x8 kf[4][2];
  #pragma unroll
  for (int jm = 0; jm < 4; ++jm) {
    kf[jm][0] = ld_frag(Kp + jm * 1024 + lane * 8);
    kf[jm][1] = ld_frag(Kp + jm * 1024 + 512 + lane * 8);
  }

  for (int jt = 0; jt < 8; ++jt) {
    // ---- V[jt] loads: issued first, consumed after S phase (latency
    //      hidden by the ~700 cyc of S-MFMA + exp below) ----
    const u16* Vb = Vp + jt * 4096;
    bf16x8 vf[4][2];
    #pragma unroll
    for (int es = 0; es < 4; ++es) {
      vf[es][0] = ld_frag(Vb + es * 512 + lane * 8);
      vf[es][1] = ld_frag(Vb + 2048 + es * 512 + lane * 8);
    }
    // ---- S^T = K*Q^T, exp2, P -> LDS (A-operand layout, trunc pack) ----
    #pragma unroll
    for (int jm = 0; jm < 4; ++jm) {
      #pragma unroll
      for (int is = 0; is < 4; ++is) {
        f32x4 c = (f32x4){0.f,0.f,0.f,0.f};
        c = MFMA(kf[jm][0], qf[is][0], c);
        c = MFMA(kf[jm][1], qf[is][1], c);
        float e0 = fexp2(c[0]), e1 = fexp2(c[1]);
        float e2 = fexp2(c[2]), e3 = fexp2(c[3]);
        lac[is] += (e0 + e1) + (e2 + e3);
        int2 pv; pv.x = tpk2(e0, e1); pv.y = tpk2(e2, e3);
        *(int2*)(pw + is * 2432 + jm * 32) = pv;
      }
    }
    // ---- K[jt+1] reload IN PLACE (WAR on kf; consumed next iteration,
    //      latency hidden by the PV phase below) ----
    {
      const u16* Kn = Kp + ((jt + 1) & 7) * 4096;
      #pragma unroll
      for (int jm = 0; jm < 4; ++jm) {
        kf[jm][0] = ld_frag(Kn + jm * 1024 + lane * 8);
        kf[jm][1] = ld_frag(Kn + jm * 1024 + 512 + lane * 8);
      }
    }
    // ---- rep += P * V ----
    #pragma unroll
    for (int m = 0; m < 4; ++m) {
      int2 a0 = *(const int2*)(pr + m * 2432);
      int2 a1 = *(const int2*)(pr + m * 2432 + 8);
      int2 a2 = *(const int2*)(pr + m * 2432 + 64);
      int2 a3 = *(const int2*)(pr + m * 2432 + 72);
      bf16x8 p0 = mk_frag(a0.x, a0.y, a1.x, a1.y);
      bf16x8 p1 = mk_frag(a2.x, a2.y, a3.x, a3.y);
      #pragma unroll
      for (int es = 0; es < 4; ++es) {
        acc[m][es] = MFMA(p0, vf[es][0], acc[m][es]);
        acc[m][es] = MFMA(p1, vf[es][1], acc[m][es]);
      }
    }
  }

  #pragma unroll
  for (int is = 0; is < 4; ++is) {
    float lv = lac[is];
    lv += __shfl_xor(lv, 16, 64);
    lv += __shfl_xor(lv, 32, 64);
    if (lane < 16) lbuf[w][is * 16 + lane] = lv;
  }
  __syncthreads();

  if (w >= 2) {
    float* s = sh.slab[w - 2];
    #pragma unroll
    for (int m = 0; m < 4; ++m)
      #pragma unroll
      for (int es = 0; es < 4; ++es)
        #pragma unroll
        for (int r = 0; r < 4; ++r)
          s[(m * 16 + q * 4 + r) * 65 + es * 16 + jl] = acc[m][es][r];
  }
  __syncthreads();
  if (w < 2) {
    const float* s = sh.slab[w];
    #pragma unroll
    for (int m = 0; m < 4; ++m)
      #pragma unroll
      for (int es = 0; es < 4; ++es)
        #pragma unroll
        for (int r = 0; r < 4; ++r)
          acc[m][es][r] += s[(m * 16 + q * 4 + r) * 65 + es * 16 + jl];
  }
  __syncthreads();
  if (w == 1) {
    float* s = sh.slab[0];
    #pragma unroll
    for (int m = 0; m < 4; ++m)
      #pragma unroll
      for (int es = 0; es < 4; ++es)
        #pragma unroll
        for (int r = 0; r < 4; ++r)
          s[(m * 16 + q * 4 + r) * 65 + es * 16 + jl] = acc[m][es][r];
  }
  __syncthreads();
  if (w == 0) {
    const float* s = sh.slab[0];
    #pragma unroll
    for (int m = 0; m < 4; ++m) {
      float il[4];
      #pragma unroll
      for (int r = 0; r < 4; ++r) {
        const int i = m * 16 + q * 4 + r;
        il[r] = 1.0f / (lbuf[0][i] + lbuf[1][i] + lbuf[2][i] + lbuf[3][i]);
      }
      const int rg = b * 128 + itile * 4 + m;
      #pragma unroll
      for (int es = 0; es < 4; ++es) {
        const int kc = h * 2 + (es >> 1);
        const int qp = (es & 1) * 2 + (jl >> 3), jj = jl & 7;
        #pragma unroll
        for (int r = 0; r < 4; ++r) {
          float val = (acc[m][es][r] + s[(m * 16 + q * 4 + r) * 65 + es * 16 + jl]) * il[r];
          Rpk[((size_t)rg * 16 + kc) * 512 + (size_t)(qp * 16 + q * 4 + r) * 8 + jj] =
              (u16)rnd1(val);
        }
      }
    }
  }
}

// ---------------------------------------------------------------------------
// Output projection: fully packed, no LDS.  grid (128 rt, 8 ot) (round-5 form).
// ---------------------------------------------------------------------------
__global__ __launch_bounds__(256) void outproj_kernel(
    const u16* __restrict__ Rpk, const u16* __restrict__ wopk,
    float* __restrict__ out)
{
  const int t = threadIdx.x, w = t >> 6, lane = t & 63;
  const int jl = lane & 15, q = lane >> 4;
  const int rt = blockIdx.x, ot = blockIdx.y;
  const int rg = rt * 4 + w;

  f32x4 acc[4];
  #pragma unroll
  for (int i = 0; i < 4; ++i) acc[i] = (f32x4){0.f,0.f,0.f,0.f};

  #pragma unroll 4
  for (int kc = 0; kc < 16; ++kc) {
    bf16x8 bf = ld_frag(Rpk + ((size_t)rg * 16 + kc) * 512 + lane * 8);
    #pragma unroll
    for (int os = 0; os < 4; ++os) {
      bf16x8 wf = ld_frag(wopk + (size_t)((ot * 16 + kc) * 4 + os) * 512 + lane * 8);
      acc[os] = MFMA(wf, bf, acc[os]);
    }
  }

  #pragma unroll
  for (int os = 0; os < 4; ++os) {   // D row = o = os*16+q*4+r, col = r-row = jl
    float4 o4 = make_float4(acc[os][0], acc[os][1], acc[os][2], acc[os][3]);
    *(float4*)&out[(size_t)(rt * 64 + w * 16 + jl) * DD + ot * 64 + os * 16 + q * 4] = o4;
  }
}

// ---------------------------------------------------------------------------
extern "C" void kernel_launch(void* const* d_in, const int* in_sizes, int n_in,
                              void* d_out, int out_size, void* d_ws, size_t ws_size,
                              hipStream_t stream)
{
  const float* x1 = (const float*)d_in[0];
  const float* x2 = (const float*)d_in[1];
  const float* vv = (const float*)d_in[2];
  const float* Wq = (const float*)d_in[3];
  const float* Wk = (const float*)d_in[4];
  const float* Wv = (const float*)d_in[5];
  const float* Wo = (const float*)d_in[6];
  float* out = (float*)d_out;

  char* W = (char*)d_ws;                        // ~58 MB total
  u16* wpk  = (u16*)(W);                        // 1.5 MB
  u16* wopk = (u16*)(W + 1572864);              // 0.5 MB
  u16* xpk  = (u16*)(W + 2097152);              // 24 MB
  u16* Qpk  = (u16*)(W + 27262976);             // 8 MB
  u16* Kpk  = (u16*)(W + 35651584);             // 8 MB
  u16* Vpk  = (u16*)(W + 44040192);             // 8 MB
  u16* Rpk  = (u16*)(W + 52428800);             // 8 MB

  pack_kernel   <<<dim3(32, 8, 14), 256, 0, stream>>>(x1, x2, vv, Wq, Wk, Wv, Wo,
                                                      xpk, wpk, wopk);
  qkvproj_kernel<<<dim3(128, 24), 256, 0, stream>>>(xpk, wpk, Qpk, Kpk, Vpk);
  attn_kernel   <<<dim3(1024), 256, 0, stream>>>(Qpk, Kpk, Vpk, Rpk);
  outproj_kernel<<<dim3(128, 8), 256, 0, stream>>>(Rpk, wopk, out);
}